// Round 1
// baseline (110.690 us; speedup 1.0000x reference)
//
#include <hip/hip_runtime.h>

// ConcatCritic: scores[i,j] = W2 . relu(x_i@W1x + y_j@W1y + b1) + b2
// B=512, DIM_X=DIM_Y=128, HIDDEN=512. fp32 in/out.
//
// R10 = structural collapse 3 kernels -> 2:
//  - reduce kernel eliminated: score atomically accumulates f32 into out
//    (out pre-filled with b2 by spare blocks of kernel A). pws16 gone.
//  - score LDS tiles transposed to [hp][row]: 4 A-rows / 4 B-cols per
//    thread come from single ds_read_b128 each -> 3 LDS instrs per 16
//    cells (was 9 b32) -> score is VALU-bound (pk_add/pk_max/fdot2).
//  - proj restructured: 2 rows x 4 h per thread, float4 LDS broadcast
//    reads + float4 W loads (was per-k scalar broadcast storm).
// Precision: partial sums now f32 (atomics), only hxy stays f16 ->
// absmax should drop below the previous 0.015625.

#define BATCH 512
#define DX    128
#define HID   512

typedef _Float16 half2_t __attribute__((ext_vector_type(2)));

static __device__ __forceinline__ half2_t u2h(unsigned int u) {
    union { unsigned int u; half2_t h; } c; c.u = u; return c.h;
}
static __device__ __forceinline__ unsigned int h2u(half2_t h) {
    union { half2_t h; unsigned int u; } c; c.h = h; return c.u;
}

// ---------------- Kernel A: projection (fp32 math, f16 out) + out-init ----
// grid (64, 3, 2), 256 thr.
//  part 0/1: proj of x/y: block = 8 rows x 256 h. thread = 2 rows x 4 h.
//  part 2:   fill out with b2[0] (128 blocks x 256 thr x 32 B).
__global__ __launch_bounds__(256) void proj_kernel(
    const float* __restrict__ x, const float* __restrict__ y,
    const float* __restrict__ W1, const float* __restrict__ b1,
    const float* __restrict__ b2,
    _Float16* __restrict__ hxy, float* __restrict__ out)
{
    const int part = blockIdx.y;
    if (part == 2) {                              // ---- out := b2 ----
        const float bs = b2[0];
        const int gid = (blockIdx.z * 64 + blockIdx.x) * 256 + threadIdx.x;
        const float4 v = make_float4(bs, bs, bs, bs);
        float4* o4 = (float4*)out;                // 65536 float4 total
        o4[gid] = v;
        o4[gid + 32768] = v;
        return;
    }

    const int row0 = blockIdx.x * 8;
    const int h0   = blockIdx.z * 256;
    const float* __restrict__ src = part ? y : x;
    const float* __restrict__ W   = W1 + part * DX * HID;

    __shared__ __align__(16) float s[8][DX];      // 4 KiB x-tile
    {
        const int t = threadIdx.x;                // 256 float4 slots
        const int r = t >> 5, c4 = (t & 31) << 2;
        *(float4*)&s[r][c4] = *(const float4*)&src[(row0 + r) * DX + c4];
    }
    __syncthreads();

    const int hthr = threadIdx.x & 63;            // 64 h-threads/wave
    const int rg   = threadIdx.x >> 6;            // wave id 0..3 -> row pair
    const int h    = h0 + hthr * 4;
    const int ra   = rg * 2, rb = ra + 1;

    float a0 = 0.f, a1 = 0.f, a2 = 0.f, a3 = 0.f; // row ra, 4 h
    float c0 = 0.f, c1 = 0.f, c2 = 0.f, c3 = 0.f; // row rb, 4 h

    #pragma unroll 2
    for (int k4 = 0; k4 < DX / 4; ++k4) {
        const float4 xa = *(const float4*)&s[ra][k4 * 4];  // b128 broadcast
        const float4 xb = *(const float4*)&s[rb][k4 * 4];
        #pragma unroll
        for (int kk = 0; kk < 4; ++kk) {
            const float4 wv = *(const float4*)&W[(k4 * 4 + kk) * HID + h];
            const float fa = (kk == 0) ? xa.x : (kk == 1) ? xa.y : (kk == 2) ? xa.z : xa.w;
            const float fb = (kk == 0) ? xb.x : (kk == 1) ? xb.y : (kk == 2) ? xb.z : xb.w;
            a0 = fmaf(fa, wv.x, a0); a1 = fmaf(fa, wv.y, a1);
            a2 = fmaf(fa, wv.z, a2); a3 = fmaf(fa, wv.w, a3);
            c0 = fmaf(fb, wv.x, c0); c1 = fmaf(fb, wv.y, c1);
            c2 = fmaf(fb, wv.z, c2); c3 = fmaf(fb, wv.w, c3);
        }
    }

    float4 bias = make_float4(0.f, 0.f, 0.f, 0.f);
    if (part) bias = *(const float4*)&b1[h];      // fold b1 into hy

    half2_t p0, p1;
    p0.x = (_Float16)(a0 + bias.x); p0.y = (_Float16)(a1 + bias.y);
    p1.x = (_Float16)(a2 + bias.z); p1.y = (_Float16)(a3 + bias.w);
    uint2 st0; st0.x = h2u(p0); st0.y = h2u(p1);
    *(uint2*)&hxy[(part * BATCH + row0 + ra) * HID + h] = st0;

    p0.x = (_Float16)(c0 + bias.x); p0.y = (_Float16)(c1 + bias.y);
    p1.x = (_Float16)(c2 + bias.z); p1.y = (_Float16)(c3 + bias.w);
    uint2 st1; st1.x = h2u(p0); st1.y = h2u(p1);
    *(uint2*)&hxy[(part * BATCH + row0 + rb) * HID + h] = st1;
}

// ---------------- Kernel B: score + f32 atomic accumulate ----------------
// grid (8, 4, 8): 128(i) x 64(j) tile, z = 8 h-chunks of 64. 512 thr,
// 4x4 cells/thread. LDS transposed [hp][row] so A-rows / B-cols are b128.
#define TI   128
#define TJ   64
#define HPW  32          // half2 per 64-h chunk
#define IST  132         // uint stride per hp-row of sA (128 + 4 pad, %4==0)
#define JST  68          // uint stride per hp-row of sB ( 64 + 4 pad, %4==0)

__global__ __launch_bounds__(512, 2) void score_kernel(
    const _Float16* __restrict__ hxy, const float* __restrict__ W2,
    float* __restrict__ out)
{
    __shared__ __align__(16) unsigned int sA[HPW * IST];   // 16.5 KiB
    __shared__ __align__(16) unsigned int sB[HPW * JST];   //  8.5 KiB
    __shared__ unsigned int sW[HPW];

    const int i0  = blockIdx.y * TI;
    const int j0  = blockIdx.x * TJ;
    const int hp0 = blockIdx.z * HPW;            // in half2 units
    const int tid = threadIdx.x;
    const unsigned int* __restrict__ hx32 = (const unsigned int*)hxy; // [row][256 hp]

    // ---- stage A: 128 rows x 32 hp, transposed write sA[hp][row]
    #pragma unroll
    for (int it = 0; it < 2; ++it) {             // 1024 uint4 slots
        const int sidx = tid + it * 512;
        const int row = sidx >> 3, q = sidx & 7;
        const uint4 v = *(const uint4*)&hx32[(i0 + row) * 256 + hp0 + (q << 2)];
        unsigned int* p = &sA[(q << 2) * IST + row];
        p[0 * IST] = v.x; p[1 * IST] = v.y; p[2 * IST] = v.z; p[3 * IST] = v.w;
    }
    // ---- stage B: 64 rows x 32 hp, transposed write sB[hp][row]
    {
        const int row = tid >> 3, q = tid & 7;   // 512 uint4 slots
        const uint4 v = *(const uint4*)&hx32[(BATCH + j0 + row) * 256 + hp0 + (q << 2)];
        unsigned int* p = &sB[(q << 2) * JST + row];
        p[0 * JST] = v.x; p[1 * JST] = v.y; p[2 * JST] = v.z; p[3 * JST] = v.w;
    }
    if (tid < HPW) {
        const float2 w = *(const float2*)&W2[2 * (hp0 + tid)];
        half2_t wh; wh.x = (_Float16)w.x; wh.y = (_Float16)w.y;
        sW[tid] = h2u(wh);
    }
    __syncthreads();

    const int tx = tid & 15;                     // 4 consecutive j each -> 64
    const int ty = tid >> 4;                     // 4 consecutive i each -> 128
    const unsigned int* pa = &sA[ty << 2];
    const unsigned int* pb = &sB[tx << 2];

    float acc[4][4] = {{0.f,0.f,0.f,0.f},{0.f,0.f,0.f,0.f},
                       {0.f,0.f,0.f,0.f},{0.f,0.f,0.f,0.f}};
    const half2_t hz = {(_Float16)0, (_Float16)0};

    #pragma unroll 4
    for (int hp = 0; hp < HPW; ++hp) {
        const half2_t w = u2h(sW[hp]);
        const uint4 av = *(const uint4*)&pa[hp * IST];   // 4 A-rows, b128
        const uint4 bv = *(const uint4*)&pb[hp * JST];   // 4 B-cols, b128
        half2_t a[4] = {u2h(av.x), u2h(av.y), u2h(av.z), u2h(av.w)};
        half2_t b[4] = {u2h(bv.x), u2h(bv.y), u2h(bv.z), u2h(bv.w)};
        #pragma unroll
        for (int r = 0; r < 4; ++r)
            #pragma unroll
            for (int c = 0; c < 4; ++c) {
                half2_t t = a[r] + b[c];                  // v_pk_add_f16
                t = __builtin_elementwise_max(t, hz);     // v_pk_max_f16
                acc[r][c] = __builtin_amdgcn_fdot2(t, w, acc[r][c], false);
            }
    }

    // ---- f32 atomic accumulate into out (pre-filled with b2)
    const int ibase = i0 + (ty << 2);
    const int jbase = j0 + (tx << 2);
    #pragma unroll
    for (int r = 0; r < 4; ++r) {
        float* orow = &out[(ibase + r) * BATCH + jbase];
        #pragma unroll
        for (int c = 0; c < 4; ++c)
            unsafeAtomicAdd(&orow[c], acc[r][c]);         // global_atomic_add_f32
    }
}

extern "C" void kernel_launch(void* const* d_in, const int* in_sizes, int n_in,
                              void* d_out, int out_size, void* d_ws, size_t ws_size,
                              hipStream_t stream) {
    const float* x  = (const float*)d_in[0];
    const float* y  = (const float*)d_in[1];
    const float* W1 = (const float*)d_in[2];
    const float* b1 = (const float*)d_in[3];
    const float* W2 = (const float*)d_in[4];
    const float* b2 = (const float*)d_in[5];
    float* out = (float*)d_out;

    _Float16* hxy = (_Float16*)d_ws;                      // 1 MiB workspace

    proj_kernel<<<dim3(64, 3, 2), 256, 0, stream>>>(x, y, W1, b1, b2, hxy, out);
    score_kernel<<<dim3(8, 4, 8), 512, 0, stream>>>(hxy, W2, out);
}

// Round 2
// 86.091 us; speedup vs baseline: 1.2857x; 1.2857x over previous
//
#include <hip/hip_runtime.h>

// ConcatCritic: scores[i,j] = W2 . relu(x_i@W1x + y_j@W1y + b1) + b2
// B=512, DIM_X=DIM_Y=128, HIDDEN=512. fp32 in/out.
//
// R11 = R9 3-kernel structure (verified 84.7 us) + R10's inner-loop wins:
//  - R10 post-mortem: 2.1M global f32 atomics (8-way contention) cost
//    ~+26 us -> reverted to f16 partial slices + reduce kernel.
//  - KEPT: score LDS transposed [hp][row], thread fragments via
//    ds_read_b128 (3 LDS instrs / 16 cells, was 9 scalar b32).
//  - KEPT: proj 2 rows x 4 h per thread, float4 broadcast LDS reads +
//    float4 W loads (was per-k scalar broadcast storm).
//  - reduce vectorized: uint2 slice loads, float4 stores, 256 blocks.

#define BATCH 512
#define DX    128
#define HID   512

typedef _Float16 half2_t __attribute__((ext_vector_type(2)));

static __device__ __forceinline__ half2_t u2h(unsigned int u) {
    union { unsigned int u; half2_t h; } c; c.u = u; return c.h;
}
static __device__ __forceinline__ unsigned int h2u(half2_t h) {
    union { half2_t h; unsigned int u; } c; c.h = h; return c.u;
}

// ---------------- Kernel A: projection (fp32 math, f16 out) ----------------
// grid (64, 2, 2), 256 thr. block = 8 rows x 256 h. thread = 2 rows x 4 h.
__global__ __launch_bounds__(256) void proj_kernel(
    const float* __restrict__ x, const float* __restrict__ y,
    const float* __restrict__ W1, const float* __restrict__ b1,
    _Float16* __restrict__ hxy)
{
    const int part = blockIdx.y;                 // 0 -> x, 1 -> y
    const int row0 = blockIdx.x * 8;
    const int h0   = blockIdx.z * 256;
    const float* __restrict__ src = part ? y : x;
    const float* __restrict__ W   = W1 + part * DX * HID;

    __shared__ __align__(16) float s[8][DX];     // 4 KiB x-tile
    {
        const int t = threadIdx.x;               // 256 float4 slots
        const int r = t >> 5, c4 = (t & 31) << 2;
        *(float4*)&s[r][c4] = *(const float4*)&src[(row0 + r) * DX + c4];
    }
    __syncthreads();

    const int hthr = threadIdx.x & 63;           // 64 h-threads/wave
    const int rg   = threadIdx.x >> 6;           // wave id 0..3 -> row pair
    const int h    = h0 + hthr * 4;
    const int ra   = rg * 2, rb = ra + 1;

    float a0 = 0.f, a1 = 0.f, a2 = 0.f, a3 = 0.f; // row ra, 4 h
    float c0 = 0.f, c1 = 0.f, c2 = 0.f, c3 = 0.f; // row rb, 4 h

    #pragma unroll 2
    for (int k4 = 0; k4 < DX / 4; ++k4) {
        const float4 xa = *(const float4*)&s[ra][k4 * 4];  // b128 broadcast
        const float4 xb = *(const float4*)&s[rb][k4 * 4];
        #pragma unroll
        for (int kk = 0; kk < 4; ++kk) {
            const float4 wv = *(const float4*)&W[(k4 * 4 + kk) * HID + h];
            const float fa = (kk == 0) ? xa.x : (kk == 1) ? xa.y : (kk == 2) ? xa.z : xa.w;
            const float fb = (kk == 0) ? xb.x : (kk == 1) ? xb.y : (kk == 2) ? xb.z : xb.w;
            a0 = fmaf(fa, wv.x, a0); a1 = fmaf(fa, wv.y, a1);
            a2 = fmaf(fa, wv.z, a2); a3 = fmaf(fa, wv.w, a3);
            c0 = fmaf(fb, wv.x, c0); c1 = fmaf(fb, wv.y, c1);
            c2 = fmaf(fb, wv.z, c2); c3 = fmaf(fb, wv.w, c3);
        }
    }

    float4 bias = make_float4(0.f, 0.f, 0.f, 0.f);
    if (part) bias = *(const float4*)&b1[h];     // fold b1 into hy

    half2_t p0, p1;
    p0.x = (_Float16)(a0 + bias.x); p0.y = (_Float16)(a1 + bias.y);
    p1.x = (_Float16)(a2 + bias.z); p1.y = (_Float16)(a3 + bias.w);
    uint2 st0; st0.x = h2u(p0); st0.y = h2u(p1);
    *(uint2*)&hxy[(part * BATCH + row0 + ra) * HID + h] = st0;

    p0.x = (_Float16)(c0 + bias.x); p0.y = (_Float16)(c1 + bias.y);
    p1.x = (_Float16)(c2 + bias.z); p1.y = (_Float16)(c3 + bias.w);
    uint2 st1; st1.x = h2u(p0); st1.y = h2u(p1);
    *(uint2*)&hxy[(part * BATCH + row0 + rb) * HID + h] = st1;
}

// ---------------- Kernel B: score -> f16 partial slices ----------------
// grid (8, 4, 8): 128(i) x 64(j) tile, z = 8 h-chunks of 64. 512 thr,
// 4x4 cells/thread. LDS transposed [hp][row]: A-rows / B-cols via b128.
#define TI   128
#define TJ   64
#define HPW  32          // half2 per 64-h chunk
#define IST  132         // uint stride per hp-row of sA (128 + 4, %4==0)
#define JST  68          // uint stride per hp-row of sB ( 64 + 4, %4==0)

__global__ __launch_bounds__(512, 2) void score_kernel(
    const _Float16* __restrict__ hxy, const float* __restrict__ W2,
    unsigned int* __restrict__ pws16)
{
    __shared__ __align__(16) unsigned int sA[HPW * IST];   // 16.5 KiB
    __shared__ __align__(16) unsigned int sB[HPW * JST];   //  8.5 KiB
    __shared__ unsigned int sW[HPW];

    const int i0  = blockIdx.y * TI;
    const int j0  = blockIdx.x * TJ;
    const int z   = blockIdx.z;
    const int hp0 = z * HPW;                     // in half2 units
    const int tid = threadIdx.x;
    const unsigned int* __restrict__ hx32 = (const unsigned int*)hxy; // [row][256 hp]

    // ---- stage A: 128 rows x 32 hp, transposed write sA[hp][row]
    #pragma unroll
    for (int it = 0; it < 2; ++it) {             // 1024 uint4 slots
        const int sidx = tid + it * 512;
        const int row = sidx >> 3, q = sidx & 7;
        const uint4 v = *(const uint4*)&hx32[(i0 + row) * 256 + hp0 + (q << 2)];
        unsigned int* p = &sA[(q << 2) * IST + row];
        p[0 * IST] = v.x; p[1 * IST] = v.y; p[2 * IST] = v.z; p[3 * IST] = v.w;
    }
    // ---- stage B: 64 rows x 32 hp, transposed write sB[hp][row]
    {
        const int row = tid >> 3, q = tid & 7;   // 512 uint4 slots
        const uint4 v = *(const uint4*)&hx32[(BATCH + j0 + row) * 256 + hp0 + (q << 2)];
        unsigned int* p = &sB[(q << 2) * JST + row];
        p[0 * JST] = v.x; p[1 * JST] = v.y; p[2 * JST] = v.z; p[3 * JST] = v.w;
    }
    if (tid < HPW) {
        const float2 w = *(const float2*)&W2[2 * (hp0 + tid)];
        half2_t wh; wh.x = (_Float16)w.x; wh.y = (_Float16)w.y;
        sW[tid] = h2u(wh);
    }
    __syncthreads();

    const int tx = tid & 15;                     // 4 consecutive j each -> 64
    const int ty = tid >> 4;                     // 4 consecutive i each -> 128
    const unsigned int* pa = &sA[ty << 2];
    const unsigned int* pb = &sB[tx << 2];

    float acc[4][4] = {{0.f,0.f,0.f,0.f},{0.f,0.f,0.f,0.f},
                       {0.f,0.f,0.f,0.f},{0.f,0.f,0.f,0.f}};
    const half2_t hz = {(_Float16)0, (_Float16)0};

    #pragma unroll 4
    for (int hp = 0; hp < HPW; ++hp) {
        const half2_t w = u2h(sW[hp]);
        const uint4 av = *(const uint4*)&pa[hp * IST];   // 4 A-rows, b128
        const uint4 bv = *(const uint4*)&pb[hp * JST];   // 4 B-cols, b128
        half2_t a[4] = {u2h(av.x), u2h(av.y), u2h(av.z), u2h(av.w)};
        half2_t b[4] = {u2h(bv.x), u2h(bv.y), u2h(bv.z), u2h(bv.w)};
        #pragma unroll
        for (int r = 0; r < 4; ++r)
            #pragma unroll
            for (int c = 0; c < 4; ++c) {
                half2_t t = a[r] + b[c];                  // v_pk_add_f16
                t = __builtin_elementwise_max(t, hz);     // v_pk_max_f16
                acc[r][c] = __builtin_amdgcn_fdot2(t, w, acc[r][c], false);
            }
    }

    // ---- f16 partial store: slice z, coalesced uint2
    const int i = i0 + (ty << 2);
    unsigned int* dst = pws16 + z * (BATCH * BATCH / 2);
    #pragma unroll
    for (int r = 0; r < 4; ++r) {
        half2_t p0, p1;
        p0.x = (_Float16)acc[r][0]; p0.y = (_Float16)acc[r][1];
        p1.x = (_Float16)acc[r][2]; p1.y = (_Float16)acc[r][3];
        uint2 st; st.x = h2u(p0); st.y = h2u(p1);
        *(uint2*)&dst[(i + r) * (BATCH / 2) + (j0 >> 1) + (tx << 1)] = st;
    }
}

// ---------------- Kernel C: reduce 8 f16 slices + b2 ----------------
// 256 blocks x 256 thr; uint2 (4 cells) per thread, float4 store.
__global__ __launch_bounds__(256) void reduce_kernel(
    const uint2* __restrict__ pws16, const float* __restrict__ b2,
    float* __restrict__ out)
{
    const int gid = blockIdx.x * 256 + threadIdx.x;      // uint2 index
    float s0 = 0.f, s1 = 0.f, s2 = 0.f, s3 = 0.f;
    #pragma unroll
    for (int zz = 0; zz < 8; ++zz) {
        const uint2 v = pws16[zz * (BATCH * BATCH / 4) + gid];
        const half2_t hA = u2h(v.x), hB = u2h(v.y);
        s0 += (float)hA.x; s1 += (float)hA.y;
        s2 += (float)hB.x; s3 += (float)hB.y;
    }
    const float bs = b2[0];
    *(float4*)&out[gid * 4] = make_float4(s0 + bs, s1 + bs, s2 + bs, s3 + bs);
}

extern "C" void kernel_launch(void* const* d_in, const int* in_sizes, int n_in,
                              void* d_out, int out_size, void* d_ws, size_t ws_size,
                              hipStream_t stream) {
    const float* x  = (const float*)d_in[0];
    const float* y  = (const float*)d_in[1];
    const float* W1 = (const float*)d_in[2];
    const float* b1 = (const float*)d_in[3];
    const float* W2 = (const float*)d_in[4];
    const float* b2 = (const float*)d_in[5];
    float* out = (float*)d_out;

    _Float16* hxy       = (_Float16*)d_ws;                          // 1 MiB
    unsigned int* pws16 = (unsigned int*)((char*)d_ws + (1 << 20)); // 4 MiB

    proj_kernel<<<dim3(BATCH / 8, 2, 2), 256, 0, stream>>>(x, y, W1, b1, hxy);
    score_kernel<<<dim3(BATCH / TJ, BATCH / TI, 8), 512, 0, stream>>>(hxy, W2, pws16);
    reduce_kernel<<<dim3(256), 256, 0, stream>>>((const uint2*)pws16, b2, out);
}

// Round 3
// 81.873 us; speedup vs baseline: 1.3520x; 1.0515x over previous
//
#include <hip/hip_runtime.h>

// ConcatCritic: scores[i,j] = W2 . relu(x_i@W1x + y_j@W1y + b1) + b2
// B=512, DIM_X=DIM_Y=128, HIDDEN=512. fp32 in/out.
//
// R12 = 2 kernels: proj (unchanged, verified) + fused score/reduce.
//  - R10/R11 post-mortem: only STRUCTURAL changes move dur_us (fill poison
//    ~40us + ~30us harness restores dominate; kernels ~10-15us). Atomics
//    (+26us) and cross-block split-K partials both rejected.
//  - score: K split across the 8 WAVES of one block (z-chunk per wave),
//    32x32 tile, grid 16x16=256 blocks. Partials combined in LDS (f16,
//    same rounding as R11 -> same absmax), b2 added, out written direct.
//    Deletes: reduce kernel launch, 4 MB partial write, 5 MB reduce read.
//  - LDS strides %4==0 (16B-aligned b128 reads), 8-row lane diversity in
//    staging keeps write conflicts at 4-way (R11-verified idiom).

#define BATCH 512
#define DX    128
#define HID   512

typedef _Float16 half2_t __attribute__((ext_vector_type(2)));

static __device__ __forceinline__ half2_t u2h(unsigned int u) {
    union { unsigned int u; half2_t h; } c; c.u = u; return c.h;
}
static __device__ __forceinline__ unsigned int h2u(half2_t h) {
    union { half2_t h; unsigned int u; } c; c.h = h; return c.u;
}

// ---------------- Kernel A: projection (fp32 math, f16 out) ----------------
// grid (64, 2, 2), 256 thr. block = 8 rows x 256 h. thread = 2 rows x 4 h.
__global__ __launch_bounds__(256) void proj_kernel(
    const float* __restrict__ x, const float* __restrict__ y,
    const float* __restrict__ W1, const float* __restrict__ b1,
    _Float16* __restrict__ hxy)
{
    const int part = blockIdx.y;                 // 0 -> x, 1 -> y
    const int row0 = blockIdx.x * 8;
    const int h0   = blockIdx.z * 256;
    const float* __restrict__ src = part ? y : x;
    const float* __restrict__ W   = W1 + part * DX * HID;

    __shared__ __align__(16) float s[8][DX];     // 4 KiB x-tile
    {
        const int t = threadIdx.x;               // 256 float4 slots
        const int r = t >> 5, c4 = (t & 31) << 2;
        *(float4*)&s[r][c4] = *(const float4*)&src[(row0 + r) * DX + c4];
    }
    __syncthreads();

    const int hthr = threadIdx.x & 63;           // 64 h-threads/wave
    const int rg   = threadIdx.x >> 6;           // wave id 0..3 -> row pair
    const int h    = h0 + hthr * 4;
    const int ra   = rg * 2, rb = ra + 1;

    float a0 = 0.f, a1 = 0.f, a2 = 0.f, a3 = 0.f; // row ra, 4 h
    float c0 = 0.f, c1 = 0.f, c2 = 0.f, c3 = 0.f; // row rb, 4 h

    #pragma unroll 2
    for (int k4 = 0; k4 < DX / 4; ++k4) {
        const float4 xa = *(const float4*)&s[ra][k4 * 4];  // b128 broadcast
        const float4 xb = *(const float4*)&s[rb][k4 * 4];
        #pragma unroll
        for (int kk = 0; kk < 4; ++kk) {
            const float4 wv = *(const float4*)&W[(k4 * 4 + kk) * HID + h];
            const float fa = (kk == 0) ? xa.x : (kk == 1) ? xa.y : (kk == 2) ? xa.z : xa.w;
            const float fb = (kk == 0) ? xb.x : (kk == 1) ? xb.y : (kk == 2) ? xb.z : xb.w;
            a0 = fmaf(fa, wv.x, a0); a1 = fmaf(fa, wv.y, a1);
            a2 = fmaf(fa, wv.z, a2); a3 = fmaf(fa, wv.w, a3);
            c0 = fmaf(fb, wv.x, c0); c1 = fmaf(fb, wv.y, c1);
            c2 = fmaf(fb, wv.z, c2); c3 = fmaf(fb, wv.w, c3);
        }
    }

    float4 bias = make_float4(0.f, 0.f, 0.f, 0.f);
    if (part) bias = *(const float4*)&b1[h];     // fold b1 into hy

    half2_t p0, p1;
    p0.x = (_Float16)(a0 + bias.x); p0.y = (_Float16)(a1 + bias.y);
    p1.x = (_Float16)(a2 + bias.z); p1.y = (_Float16)(a3 + bias.w);
    uint2 st0; st0.x = h2u(p0); st0.y = h2u(p1);
    *(uint2*)&hxy[(part * BATCH + row0 + ra) * HID + h] = st0;

    p0.x = (_Float16)(c0 + bias.x); p0.y = (_Float16)(c1 + bias.y);
    p1.x = (_Float16)(c2 + bias.z); p1.y = (_Float16)(c3 + bias.w);
    uint2 st1; st1.x = h2u(p0); st1.y = h2u(p1);
    *(uint2*)&hxy[(part * BATCH + row0 + rb) * HID + h] = st1;
}

// ---------------- Kernel B: fused score + in-block reduce ----------------
// grid (16,16), 512 thr (8 waves). 32(i) x 32(j) tile, full H=512.
// Wave w computes h-chunk [w*64, w*64+64); per lane 4x4 cells via b128
// fragment reads (same inner loop as R11). Partials -> LDS f16 -> summed,
// + b2, direct out write.
#define TI   32
#define TJ   32
#define AST  36      // uint stride per hp-row (32 + 4 pad, %4==0 for b128)
#define PST  17      // uint stride per i-row of partial slice (16 + 1)

__global__ __launch_bounds__(512) void score_kernel(
    const _Float16* __restrict__ hxy, const float* __restrict__ W2,
    const float* __restrict__ b2, float* __restrict__ out)
{
    __shared__ __align__(16) unsigned int sA[256 * AST];   // 36 KiB
    __shared__ __align__(16) unsigned int sB[256 * AST];   // 36 KiB
    __shared__ unsigned int sW[256];                       //  1 KiB
    __shared__ unsigned int pP[8][TI * PST];               // 17 KiB

    const int i0  = blockIdx.y * TI;
    const int j0  = blockIdx.x * TJ;
    const int tid = threadIdx.x;
    const unsigned int* __restrict__ hx32 = (const unsigned int*)hxy; // [row][256 hp]

    // ---- stage A & B: 32 rows x 64 uint4 each, transposed [hp][row].
    // sidx bits: q8 = low 3 (uint4 within 128B chunk), row = mid 5,
    // chunk = high 3 (hp-chunk). Wave touches 8 rows -> 4-way write conflict.
    #pragma unroll
    for (int it = 0; it < 4; ++it) {
        const int sidx  = tid + it * 512;        // 0..2047
        const int q8    = sidx & 7;
        const int row   = (sidx >> 3) & 31;
        const int chunk = sidx >> 8;
        const int q     = chunk * 8 + q8;        // uint4 index 0..63 (hp = 4q)
        const uint4 va = *(const uint4*)&hx32[(i0 + row) * 256 + (q << 2)];
        unsigned int* pa = &sA[(q << 2) * AST + row];
        pa[0 * AST] = va.x; pa[1 * AST] = va.y; pa[2 * AST] = va.z; pa[3 * AST] = va.w;
        const uint4 vb = *(const uint4*)&hx32[(BATCH + j0 + row) * 256 + (q << 2)];
        unsigned int* pb = &sB[(q << 2) * AST + row];
        pb[0 * AST] = vb.x; pb[1 * AST] = vb.y; pb[2 * AST] = vb.z; pb[3 * AST] = vb.w;
    }
    if (tid < 256) {
        const float2 w = *(const float2*)&W2[2 * tid];
        half2_t wh; wh.x = (_Float16)w.x; wh.y = (_Float16)w.y;
        sW[tid] = h2u(wh);
    }
    __syncthreads();

    const int wave = tid >> 6;                   // z-chunk 0..7
    const int lane = tid & 63;
    const int tx   = lane & 7;                   // 4 j-cols -> 32
    const int ty   = lane >> 3;                  // 4 i-rows -> 32
    const int hp0  = wave * 32;                  // half2 base of this chunk

    const unsigned int* pa = &sA[ty << 2];
    const unsigned int* pb = &sB[tx << 2];

    float acc[4][4] = {{0.f,0.f,0.f,0.f},{0.f,0.f,0.f,0.f},
                       {0.f,0.f,0.f,0.f},{0.f,0.f,0.f,0.f}};
    const half2_t hz = {(_Float16)0, (_Float16)0};

    #pragma unroll 4
    for (int hpl = 0; hpl < 32; ++hpl) {
        const int hp = hp0 + hpl;
        const half2_t w = u2h(sW[hp]);
        const uint4 av = *(const uint4*)&pa[hp * AST];   // 4 A-rows, b128
        const uint4 bv = *(const uint4*)&pb[hp * AST];   // 4 B-cols, b128
        half2_t a[4] = {u2h(av.x), u2h(av.y), u2h(av.z), u2h(av.w)};
        half2_t b[4] = {u2h(bv.x), u2h(bv.y), u2h(bv.z), u2h(bv.w)};
        #pragma unroll
        for (int r = 0; r < 4; ++r)
            #pragma unroll
            for (int c = 0; c < 4; ++c) {
                half2_t t = a[r] + b[c];                  // v_pk_add_f16
                t = __builtin_elementwise_max(t, hz);     // v_pk_max_f16
                acc[r][c] = __builtin_amdgcn_fdot2(t, w, acc[r][c], false);
            }
    }

    // ---- partials -> LDS (f16, same rounding as R11's global partials)
    {
        unsigned int* pz = &pP[wave][0];
        #pragma unroll
        for (int r = 0; r < 4; ++r) {
            half2_t p0, p1;
            p0.x = (_Float16)acc[r][0]; p0.y = (_Float16)acc[r][1];
            p1.x = (_Float16)acc[r][2]; p1.y = (_Float16)acc[r][3];
            const int irow = (ty << 2) + r;
            pz[irow * PST + (tx << 1)]     = h2u(p0);
            pz[irow * PST + (tx << 1) + 1] = h2u(p1);
        }
    }
    __syncthreads();

    // ---- in-block reduce: thread t sums 8 slices for 2 cells, + b2
    {
        const int i  = tid >> 4;                 // 0..31
        const int jp = tid & 15;                 // uint (2 cells) 0..15
        float s0 = 0.f, s1 = 0.f;
        #pragma unroll
        for (int z = 0; z < 8; ++z) {
            const half2_t v = u2h(pP[z][i * PST + jp]);
            s0 += (float)v.x; s1 += (float)v.y;
        }
        const float bs = b2[0];
        *(float2*)&out[(i0 + i) * BATCH + j0 + (jp << 1)] =
            make_float2(s0 + bs, s1 + bs);
    }
}

extern "C" void kernel_launch(void* const* d_in, const int* in_sizes, int n_in,
                              void* d_out, int out_size, void* d_ws, size_t ws_size,
                              hipStream_t stream) {
    const float* x  = (const float*)d_in[0];
    const float* y  = (const float*)d_in[1];
    const float* W1 = (const float*)d_in[2];
    const float* b1 = (const float*)d_in[3];
    const float* W2 = (const float*)d_in[4];
    const float* b2 = (const float*)d_in[5];
    float* out = (float*)d_out;

    _Float16* hxy = (_Float16*)d_ws;             // 1 MiB workspace used

    proj_kernel<<<dim3(BATCH / 8, 2, 2), 256, 0, stream>>>(x, y, W1, b1, hxy);
    score_kernel<<<dim3(BATCH / TJ, BATCH / TI), 512, 0, stream>>>(hxy, W2, b2, out);
}

// Round 4
// 81.857 us; speedup vs baseline: 1.3522x; 1.0002x over previous
//
#include <hip/hip_runtime.h>

// ConcatCritic: scores[i,j] = W2 . relu(x_i@W1x + y_j@W1y + b1) + b2
// B=512, DIM_X=DIM_Y=128, HIDDEN=512. fp32 in/out.
//
// R13 = R12 (verified 81.9 us) + proj occupancy fix.
//  - R12 post-mortem: structure lever confirmed (-4.2 us for one launch +
//    9 MB round-trip). Remaining window ~= 40us ws-poison + ~30us harness
//    restores + ~10-12us ours. Full fusion rejected: per-block W1 re-read
//    from L2 is ~3.8us serial (512KB @ ~135GB/s per CU) > launch saving.
//  - proj: was 256 blocks x 4 waves = 1 wave/SIMD, latency-bound on 128
//    L2-hit W loads/thread. Now 4-row blocks, grid(128,2,2)=512 blocks
//    -> 2 waves/SIMD, same instr totals, 2x latency hiding.
//  - score: byte-identical to R12's verified fused score+reduce.

#define BATCH 512
#define DX    128
#define HID   512

typedef _Float16 half2_t __attribute__((ext_vector_type(2)));

static __device__ __forceinline__ half2_t u2h(unsigned int u) {
    union { unsigned int u; half2_t h; } c; c.u = u; return c.h;
}
static __device__ __forceinline__ unsigned int h2u(half2_t h) {
    union { half2_t h; unsigned int u; } c; c.h = h; return c.u;
}

// ---------------- Kernel A: projection (fp32 math, f16 out) ----------------
// grid (128, 2, 2), 256 thr. block = 4 rows x 256 h. thread = 1 row x 4 h.
// 512 blocks -> 2 blocks/CU -> 2 waves/SIMD (latency hiding for W loads).
__global__ __launch_bounds__(256) void proj_kernel(
    const float* __restrict__ x, const float* __restrict__ y,
    const float* __restrict__ W1, const float* __restrict__ b1,
    _Float16* __restrict__ hxy)
{
    const int part = blockIdx.y;                 // 0 -> x, 1 -> y
    const int row0 = blockIdx.x * 4;
    const int h0   = blockIdx.z * 256;
    const float* __restrict__ src = part ? y : x;
    const float* __restrict__ W   = W1 + part * DX * HID;

    __shared__ __align__(16) float s[4][DX];     // 2 KiB x-tile
    if (threadIdx.x < 128) {                     // 128 float4 slots
        const int t = threadIdx.x;
        const int r = t >> 5, c4 = (t & 31) << 2;
        *(float4*)&s[r][c4] = *(const float4*)&src[(row0 + r) * DX + c4];
    }
    __syncthreads();

    const int h = h0 + (threadIdx.x & 63) * 4;   // 64 h-threads/wave
    const int r = threadIdx.x >> 6;              // wave id 0..3 -> row

    float a0 = 0.f, a1 = 0.f, a2 = 0.f, a3 = 0.f;

    #pragma unroll 4
    for (int k4 = 0; k4 < DX / 4; ++k4) {
        const float4 xa = *(const float4*)&s[r][k4 * 4];   // b128 broadcast
        #pragma unroll
        for (int kk = 0; kk < 4; ++kk) {
            const float4 wv = *(const float4*)&W[(k4 * 4 + kk) * HID + h];
            const float fa = (kk == 0) ? xa.x : (kk == 1) ? xa.y : (kk == 2) ? xa.z : xa.w;
            a0 = fmaf(fa, wv.x, a0); a1 = fmaf(fa, wv.y, a1);
            a2 = fmaf(fa, wv.z, a2); a3 = fmaf(fa, wv.w, a3);
        }
    }

    float4 bias = make_float4(0.f, 0.f, 0.f, 0.f);
    if (part) bias = *(const float4*)&b1[h];     // fold b1 into hy

    half2_t p0, p1;
    p0.x = (_Float16)(a0 + bias.x); p0.y = (_Float16)(a1 + bias.y);
    p1.x = (_Float16)(a2 + bias.z); p1.y = (_Float16)(a3 + bias.w);
    uint2 st; st.x = h2u(p0); st.y = h2u(p1);
    *(uint2*)&hxy[(part * BATCH + row0 + r) * HID + h] = st;
}

// ---------------- Kernel B: fused score + in-block reduce ----------------
// grid (16,16), 512 thr (8 waves). 32(i) x 32(j) tile, full H=512.
// Wave w computes h-chunk [w*64, w*64+64); per lane 4x4 cells via b128
// fragment reads. Partials -> LDS f16 -> summed, + b2, direct out write.
#define TI   32
#define TJ   32
#define AST  36      // uint stride per hp-row (32 + 4 pad, %4==0 for b128)
#define PST  17      // uint stride per i-row of partial slice (16 + 1)

__global__ __launch_bounds__(512) void score_kernel(
    const _Float16* __restrict__ hxy, const float* __restrict__ W2,
    const float* __restrict__ b2, float* __restrict__ out)
{
    __shared__ __align__(16) unsigned int sA[256 * AST];   // 36 KiB
    __shared__ __align__(16) unsigned int sB[256 * AST];   // 36 KiB
    __shared__ unsigned int sW[256];                       //  1 KiB
    __shared__ unsigned int pP[8][TI * PST];               // 17 KiB

    const int i0  = blockIdx.y * TI;
    const int j0  = blockIdx.x * TJ;
    const int tid = threadIdx.x;
    const unsigned int* __restrict__ hx32 = (const unsigned int*)hxy; // [row][256 hp]

    // ---- stage A & B: 32 rows x 64 uint4 each, transposed [hp][row].
    #pragma unroll
    for (int it = 0; it < 4; ++it) {
        const int sidx  = tid + it * 512;        // 0..2047
        const int q8    = sidx & 7;
        const int row   = (sidx >> 3) & 31;
        const int chunk = sidx >> 8;
        const int q     = chunk * 8 + q8;        // uint4 index 0..63 (hp = 4q)
        const uint4 va = *(const uint4*)&hx32[(i0 + row) * 256 + (q << 2)];
        unsigned int* pa = &sA[(q << 2) * AST + row];
        pa[0 * AST] = va.x; pa[1 * AST] = va.y; pa[2 * AST] = va.z; pa[3 * AST] = va.w;
        const uint4 vb = *(const uint4*)&hx32[(BATCH + j0 + row) * 256 + (q << 2)];
        unsigned int* pb = &sB[(q << 2) * AST + row];
        pb[0 * AST] = vb.x; pb[1 * AST] = vb.y; pb[2 * AST] = vb.z; pb[3 * AST] = vb.w;
    }
    if (tid < 256) {
        const float2 w = *(const float2*)&W2[2 * tid];
        half2_t wh; wh.x = (_Float16)w.x; wh.y = (_Float16)w.y;
        sW[tid] = h2u(wh);
    }
    __syncthreads();

    const int wave = tid >> 6;                   // z-chunk 0..7
    const int lane = tid & 63;
    const int tx   = lane & 7;                   // 4 j-cols -> 32
    const int ty   = lane >> 3;                  // 4 i-rows -> 32
    const int hp0  = wave * 32;                  // half2 base of this chunk

    const unsigned int* pa = &sA[ty << 2];
    const unsigned int* pb = &sB[tx << 2];

    float acc[4][4] = {{0.f,0.f,0.f,0.f},{0.f,0.f,0.f,0.f},
                       {0.f,0.f,0.f,0.f},{0.f,0.f,0.f,0.f}};
    const half2_t hz = {(_Float16)0, (_Float16)0};

    #pragma unroll 4
    for (int hpl = 0; hpl < 32; ++hpl) {
        const int hp = hp0 + hpl;
        const half2_t w = u2h(sW[hp]);
        const uint4 av = *(const uint4*)&pa[hp * AST];   // 4 A-rows, b128
        const uint4 bv = *(const uint4*)&pb[hp * AST];   // 4 B-cols, b128
        half2_t a[4] = {u2h(av.x), u2h(av.y), u2h(av.z), u2h(av.w)};
        half2_t b[4] = {u2h(bv.x), u2h(bv.y), u2h(bv.z), u2h(bv.w)};
        #pragma unroll
        for (int r = 0; r < 4; ++r)
            #pragma unroll
            for (int c = 0; c < 4; ++c) {
                half2_t t = a[r] + b[c];                  // v_pk_add_f16
                t = __builtin_elementwise_max(t, hz);     // v_pk_max_f16
                acc[r][c] = __builtin_amdgcn_fdot2(t, w, acc[r][c], false);
            }
    }

    // ---- partials -> LDS (f16)
    {
        unsigned int* pz = &pP[wave][0];
        #pragma unroll
        for (int r = 0; r < 4; ++r) {
            half2_t p0, p1;
            p0.x = (_Float16)acc[r][0]; p0.y = (_Float16)acc[r][1];
            p1.x = (_Float16)acc[r][2]; p1.y = (_Float16)acc[r][3];
            const int irow = (ty << 2) + r;
            pz[irow * PST + (tx << 1)]     = h2u(p0);
            pz[irow * PST + (tx << 1) + 1] = h2u(p1);
        }
    }
    __syncthreads();

    // ---- in-block reduce: thread t sums 8 slices for 2 cells, + b2
    {
        const int i  = tid >> 4;                 // 0..31
        const int jp = tid & 15;                 // uint (2 cells) 0..15
        float s0 = 0.f, s1 = 0.f;
        #pragma unroll
        for (int z = 0; z < 8; ++z) {
            const half2_t v = u2h(pP[z][i * PST + jp]);
            s0 += (float)v.x; s1 += (float)v.y;
        }
        const float bs = b2[0];
        *(float2*)&out[(i0 + i) * BATCH + j0 + (jp << 1)] =
            make_float2(s0 + bs, s1 + bs);
    }
}

extern "C" void kernel_launch(void* const* d_in, const int* in_sizes, int n_in,
                              void* d_out, int out_size, void* d_ws, size_t ws_size,
                              hipStream_t stream) {
    const float* x  = (const float*)d_in[0];
    const float* y  = (const float*)d_in[1];
    const float* W1 = (const float*)d_in[2];
    const float* b1 = (const float*)d_in[3];
    const float* W2 = (const float*)d_in[4];
    const float* b2 = (const float*)d_in[5];
    float* out = (float*)d_out;

    _Float16* hxy = (_Float16*)d_ws;             // 1 MiB workspace used

    proj_kernel<<<dim3(BATCH / 4, 2, 2), 256, 0, stream>>>(x, y, W1, b1, hxy);
    score_kernel<<<dim3(BATCH / TJ, BATCH / TI), 512, 0, stream>>>(hxy, W2, b2, out);
}